// Round 1
// baseline (777.149 us; speedup 1.0000x reference)
//
#include <hip/hip_runtime.h>
#include <math.h>

// Problem constants (fixed by reference)
#define B_TOT   256
#define N_TOT   2304
#define IN_DIM  8
#define NC      10      // NUM_CLASSES
#define OD      16      // OUT_DIM
#define CD      160     // NC*OD
#define RBIAS   0.1f

// Tiling
#define BTILE    32
#define NSLICES  64
#define NPB      (N_TOT / NSLICES)       // 36 capsules per block
#define NTHREADS 320                     // BTILE * NC
#define XROW     (NPB * IN_DIM + 4)      // 292: +4 pad breaks 32-bank stride
#define CPAD     20                      // class stride in sh_W (c*20 % 32 -> 2-way max)
#define WROW     (NC * CPAD)             // 200 floats per i-row

// One routing round:
//   logits[b,n,c] = dot(u_hat[b,n,c,:], S_acc[b,c,:])   (u_hat recomputed from x,W)
//   cw = softmax_c(logits);  s_out[b,c,d] += sum_n cw * u_hat[b,n,c,d]  (atomic)
// Round 0: S_acc == 0 -> logits 0 -> cw = 1/10 exactly, matching softmax(zeros).
__global__ __launch_bounds__(NTHREADS) void routing_round(
    const float* __restrict__ x,      // [B, N, 8]
    const float* __restrict__ W,      // [N, 8, 160]
    const float* __restrict__ S_acc,  // [B, 160]  sum of previous s (bias included)
    float* __restrict__ s_out)        // [B, 160]  atomic accumulation target
{
    __shared__ float sh_x[BTILE * XROW];
    __shared__ float sh_W[IN_DIM * WROW];
    __shared__ float sh_logit[BTILE * 12];

    const int tid = threadIdx.x;
    const int b0  = blockIdx.x * BTILE;
    const int n0  = blockIdx.y * NPB;
    const int b_l = tid / NC;
    const int c   = tid - b_l * NC;

    // ---- stage x tile: [BTILE][NPB*8] (contiguous per b), float4, coalesced
    const int XT4 = BTILE * NPB * IN_DIM / 4;       // 2304 float4
    for (int k = tid; k < XT4; k += NTHREADS) {
        int bb   = k / (NPB * 2);                   // 72 float4 per b-row
        int off4 = k - bb * (NPB * 2);
        float4 v = *(const float4*)(x + ((size_t)(b0 + bb) * N_TOT + n0) * IN_DIM + off4 * 4);
        *(float4*)(&sh_x[bb * XROW + off4 * 4]) = v;
    }

    // ---- S_acc fragment for this (b,c) into registers (16 regs)
    float S[OD];
    {
        const float4* p = (const float4*)(S_acc + (size_t)(b0 + b_l) * CD + c * OD);
        #pragma unroll
        for (int j = 0; j < 4; j++) ((float4*)S)[j] = p[j];
    }

    float acc[OD];
    #pragma unroll
    for (int d = 0; d < OD; d++) acc[d] = 0.f;

    // ---- per-thread W staging map: one float4 per n (1280 floats / 320 threads)
    const int e  = tid * 4;                 // element index in W[n] row
    const int wi = e / CD;                  // input dim 0..7
    const int wr = e - wi * CD;
    const int wc = wr / OD;
    const int wd = wr - wc * OD;
    const int w_lds = wi * WROW + wc * CPAD + wd;   // multiple of 4 -> float4 ok

    for (int nn = 0; nn < NPB; nn++) {
        // stage W[n0+nn] (5 KB), fully coalesced, one dwordx4 per thread
        {
            float4 wv = *(const float4*)(W + (size_t)(n0 + nn) * (IN_DIM * CD) + e);
            *(float4*)(&sh_W[w_lds]) = wv;
        }
        __syncthreads();   // sync A: W staged (also covers sh_x on first iter)

        // u_hat[c, 0..15] for this (b,n)
        float u[OD];
        #pragma unroll
        for (int d = 0; d < OD; d++) u[d] = 0.f;
        #pragma unroll
        for (int i = 0; i < IN_DIM; i++) {
            float xv = sh_x[b_l * XROW + nn * IN_DIM + i];
            const float* wp = &sh_W[i * WROW + c * CPAD];
            float4 w0 = *(const float4*)(wp);
            float4 w1 = *(const float4*)(wp + 4);
            float4 w2 = *(const float4*)(wp + 8);
            float4 w3 = *(const float4*)(wp + 12);
            u[0]  += xv * w0.x;  u[1]  += xv * w0.y;  u[2]  += xv * w0.z;  u[3]  += xv * w0.w;
            u[4]  += xv * w1.x;  u[5]  += xv * w1.y;  u[6]  += xv * w1.z;  u[7]  += xv * w1.w;
            u[8]  += xv * w2.x;  u[9]  += xv * w2.y;  u[10] += xv * w2.z;  u[11] += xv * w2.w;
            u[12] += xv * w3.x;  u[13] += xv * w3.y;  u[14] += xv * w3.z;  u[15] += xv * w3.w;
        }

        // routing logit = dot(u, S)
        float lg = 0.f;
        #pragma unroll
        for (int d = 0; d < OD; d++) lg += u[d] * S[d];
        sh_logit[b_l * 12 + c] = lg;
        __syncthreads();   // sync B: logits visible; also fences sh_W reads before next stage

        // softmax over the 10 classes (each thread redundantly reduces its row)
        float m = -1e30f;
        #pragma unroll
        for (int j = 0; j < NC; j++) m = fmaxf(m, sh_logit[b_l * 12 + j]);
        float ssum = 0.f;
        #pragma unroll
        for (int j = 0; j < NC; j++) ssum += __expf(sh_logit[b_l * 12 + j] - m);
        float cw = __expf(lg - m) / ssum;

        #pragma unroll
        for (int d = 0; d < OD; d++) acc[d] += cw * u[d];
    }

    // one atomic per (block, b, c, d); 64 blocks contend per address
    float* dst = s_out + (size_t)(b0 + b_l) * CD + c * OD;
    #pragma unroll
    for (int d = 0; d < OD; d++) atomicAdd(dst + d, acc[d]);
}

// Adds routing bias; folds s into S_acc (rounds 0,1) or squashes to output (round 2).
__global__ __launch_bounds__(256) void fixup(
    const float* __restrict__ s_partial,
    float* __restrict__ S_acc,
    float* __restrict__ v_out,
    int is_final)
{
    int idx = blockIdx.x * 256 + threadIdx.x;   // 40960 = B*CD
    float s = s_partial[idx] + RBIAS;
    if (!is_final) {
        S_acc[idx] += s;
    } else {
        // squash over the 16 out-dims: groups of 16 consecutive lanes
        float ss = s * s;
        #pragma unroll
        for (int off = 1; off < 16; off <<= 1)
            ss += __shfl_xor(ss, off, 64);
        float norm = sqrtf(ss);
        v_out[idx] = s * norm / (1.0f + ss);
    }
}

extern "C" void kernel_launch(void* const* d_in, const int* in_sizes, int n_in,
                              void* d_out, int out_size, void* d_ws, size_t ws_size,
                              hipStream_t stream) {
    const float* x = (const float*)d_in[0];   // [256,2304,8]
    const float* W = (const float*)d_in[1];   // [2304,8,160]
    float* out = (float*)d_out;               // [256,10,16]

    float* S_acc     = (float*)d_ws;                  // 40960 floats
    float* s_partial = S_acc + (size_t)B_TOT * CD;    // 40960 floats

    hipMemsetAsync(S_acc, 0, (size_t)B_TOT * CD * sizeof(float), stream);

    for (int r = 0; r < 3; r++) {
        hipMemsetAsync(s_partial, 0, (size_t)B_TOT * CD * sizeof(float), stream);
        routing_round<<<dim3(B_TOT / BTILE, NSLICES), NTHREADS, 0, stream>>>(
            x, W, S_acc, s_partial);
        fixup<<<(B_TOT * CD) / 256, 256, 0, stream>>>(s_partial, S_acc, out, r == 2);
    }
}

// Round 2
// 759.624 us; speedup vs baseline: 1.0231x; 1.0231x over previous
//
#include <hip/hip_runtime.h>
#include <math.h>

// Problem constants (fixed by reference)
#define B_TOT   256
#define N_TOT   2304
#define IN_DIM  8
#define NC      10      // NUM_CLASSES
#define OD      16      // OUT_DIM
#define CD      160     // NC*OD
#define RBIAS   0.1f

// Tiling
#define BTILE    64                      // b per block
#define VB       4                       // b per thread
#define NS       128                     // n-slices (grid.y)
#define NPB      (N_TOT / NS)            // 18 n per block
#define NTHREADS 320                     // (BTILE/VB)=16 p  ×  10 c  ×  2 dh
#define CPAD     20                      // class stride in sh_W (<=3-way bank alias)
#define WROW     (NC * CPAD)             // 200 floats per i-row
#define WBUF     (IN_DIM * WROW)         // 1600 floats per n
#define LROW     13                      // logit row pad (13 coprime 32)
#define NREP     8                       // s_partial replicas (atomic contention /8)

// One routing round. Thread (p,c,dh) owns b = b0+p*4+{0..3}, class c, d-half dh.
//   u[b,n,c,d] recomputed from x,W (W staged in LDS, double-buffered, 1 barrier/n)
//   logit = dot(u, S_acc[b,c,:]) (partner half via shfl_xor(1))
//   cw = softmax_c(logit);  acc += cw*u;  atomics at end.
// FIRST=1: cw = 1/10 exactly (softmax of zeros) — no S/logits at all.
template <int FIRST>
__global__ __launch_bounds__(NTHREADS, 3) void routing_round(
    const float* __restrict__ x,      // [B, N, 8]
    const float* __restrict__ W,      // [N, 8, 160]
    const float* __restrict__ S_acc,  // [B, 160]
    float* __restrict__ s_out)        // [NREP, B, 160]
{
    __shared__ float sh_W[2][WBUF];            // 12.8 KB
    __shared__ float sh_lg[2][BTILE * LROW];   // 6.7 KB

    const int tid = threadIdx.x;
    const int b0  = blockIdx.x * BTILE;
    const int n0  = blockIdx.y * NPB;
    const int p   = tid / 20;
    const int rem = tid - p * 20;
    const int c   = rem >> 1;
    const int dh  = rem & 1;
    const int bbase = b0 + p * VB;

    // S fragment: [4 b][8 d]
    float S[VB][8];
    if (!FIRST) {
        #pragma unroll
        for (int j = 0; j < VB; j++) {
            const float4* sp = (const float4*)(S_acc + (size_t)(bbase + j) * CD + c * OD + dh * 8);
            ((float4*)S[j])[0] = sp[0];
            ((float4*)S[j])[1] = sp[1];
        }
    }

    float acc[VB][8];
    #pragma unroll
    for (int j = 0; j < VB; j++)
        #pragma unroll
        for (int d = 0; d < 8; d++) acc[j][d] = 0.f;

    // W staging map: thread stages floats [e, e+4) of the 1280-float n-row
    const int e  = tid * 4;
    const int wi = e / CD;
    const int wr = e - wi * CD;
    const int wc = wr >> 4;
    const int wd = wr & 15;
    const int wlds = wi * WROW + wc * CPAD + wd;    // 16B-aligned (mult of 4 floats)
    const float* Wbase = W + (size_t)n0 * (IN_DIM * CD);

    // prologue: stage W row n0 into buffer 0
    {
        float4 wv = *(const float4*)(Wbase + e);
        *(float4*)&sh_W[0][wlds] = wv;
    }
    __syncthreads();

    for (int nn = 0; nn < NPB; nn++) {
        const int cur = nn & 1, nxt = cur ^ 1;

        // prefetch next W row into registers (latency hidden by compute)
        float4 wnext;
        if (nn + 1 < NPB)
            wnext = *(const float4*)(Wbase + (size_t)(nn + 1) * (IN_DIM * CD) + e);

        // x rows for my 4 b's (20 lanes share each row -> coalesced + L1)
        float xr[VB][8];
        #pragma unroll
        for (int j = 0; j < VB; j++) {
            const float4* xp = (const float4*)(x + ((size_t)(bbase + j) * N_TOT + n0 + nn) * IN_DIM);
            ((float4*)xr[j])[0] = xp[0];
            ((float4*)xr[j])[1] = xp[1];
        }

        // u[4 b][8 d] from LDS W fragment (each b128 feeds 16 fma)
        float u[VB][8];
        #pragma unroll
        for (int j = 0; j < VB; j++)
            #pragma unroll
            for (int d = 0; d < 8; d++) u[j][d] = 0.f;

        const float* wb = &sh_W[cur][c * CPAD + dh * 8];
        #pragma unroll
        for (int i = 0; i < IN_DIM; i++) {
            float4 w0 = *(const float4*)(wb + i * WROW);
            float4 w1 = *(const float4*)(wb + i * WROW + 4);
            #pragma unroll
            for (int j = 0; j < VB; j++) {
                float xv = xr[j][i];
                u[j][0] += xv * w0.x;  u[j][1] += xv * w0.y;
                u[j][2] += xv * w0.z;  u[j][3] += xv * w0.w;
                u[j][4] += xv * w1.x;  u[j][5] += xv * w1.y;
                u[j][6] += xv * w1.z;  u[j][7] += xv * w1.w;
            }
        }

        float lg[VB];
        if (!FIRST) {
            #pragma unroll
            for (int j = 0; j < VB; j++) {
                float t = 0.f;
                #pragma unroll
                for (int d = 0; d < 8; d++) t += u[j][d] * S[j][d];
                t += __shfl_xor(t, 1, 64);      // partner d-half (adjacent lane)
                lg[j] = t;
            }
            if (dh == 0) {
                #pragma unroll
                for (int j = 0; j < VB; j++)
                    sh_lg[cur][(p * VB + j) * LROW + c] = lg[j];
            }
        }

        // stage next W into the other buffer (visible after barrier)
        if (nn + 1 < NPB)
            *(float4*)&sh_W[nxt][wlds] = wnext;

        __syncthreads();   // the ONLY barrier per n

        float cw[VB];
        if (!FIRST) {
            #pragma unroll
            for (int j = 0; j < VB; j++) {
                const float* row = &sh_lg[cur][(p * VB + j) * LROW];
                float m = row[0];
                #pragma unroll
                for (int k = 1; k < NC; k++) m = fmaxf(m, row[k]);
                float ssum = 0.f;
                #pragma unroll
                for (int k = 0; k < NC; k++) ssum += __expf(row[k] - m);
                cw[j] = __expf(lg[j] - m) / ssum;
            }
        } else {
            #pragma unroll
            for (int j = 0; j < VB; j++) cw[j] = 0.1f;
        }

        #pragma unroll
        for (int j = 0; j < VB; j++)
            #pragma unroll
            for (int d = 0; d < 8; d++) acc[j][d] += cw[j] * u[j][d];
    }

    // flush: 32 atomics/thread to one of 8 replicas (16 blocks contend/address)
    float* dst = s_out + (size_t)(blockIdx.y & (NREP - 1)) * (B_TOT * CD);
    #pragma unroll
    for (int j = 0; j < VB; j++) {
        float* row = dst + (size_t)(bbase + j) * CD + c * OD + dh * 8;
        #pragma unroll
        for (int d = 0; d < 8; d++) atomicAdd(row + d, acc[j][d]);
    }
}

// Sums replicas + bias; folds into S_acc (rounds 0,1) or squashes to output (round 2).
__global__ __launch_bounds__(256) void fixup(
    const float* __restrict__ s_partial,   // [NREP, B, 160]
    float* __restrict__ S_acc,
    float* __restrict__ v_out,
    int is_final)
{
    int idx = blockIdx.x * 256 + threadIdx.x;   // 40960 = B*CD
    float s = RBIAS;
    #pragma unroll
    for (int r = 0; r < NREP; r++) s += s_partial[(size_t)r * (B_TOT * CD) + idx];
    if (!is_final) {
        S_acc[idx] += s;
    } else {
        float ss = s * s;   // squash over 16 consecutive lanes (one (b,c) row)
        #pragma unroll
        for (int off = 1; off < 16; off <<= 1)
            ss += __shfl_xor(ss, off, 64);
        float norm = sqrtf(ss);
        v_out[idx] = s * norm / (1.0f + ss);
    }
}

extern "C" void kernel_launch(void* const* d_in, const int* in_sizes, int n_in,
                              void* d_out, int out_size, void* d_ws, size_t ws_size,
                              hipStream_t stream) {
    const float* x = (const float*)d_in[0];   // [256,2304,8]
    const float* W = (const float*)d_in[1];   // [2304,8,160]
    float* out = (float*)d_out;               // [256,10,16]

    float* S_acc     = (float*)d_ws;                       // 40960 floats
    float* s_partial = S_acc + (size_t)B_TOT * CD;         // NREP * 40960 floats

    hipMemsetAsync(S_acc, 0, (size_t)B_TOT * CD * sizeof(float), stream);

    for (int r = 0; r < 3; r++) {
        hipMemsetAsync(s_partial, 0, (size_t)NREP * B_TOT * CD * sizeof(float), stream);
        if (r == 0)
            routing_round<1><<<dim3(B_TOT / BTILE, NS), NTHREADS, 0, stream>>>(x, W, S_acc, s_partial);
        else
            routing_round<0><<<dim3(B_TOT / BTILE, NS), NTHREADS, 0, stream>>>(x, W, S_acc, s_partial);
        fixup<<<(B_TOT * CD) / 256, 256, 0, stream>>>(s_partial, S_acc, out, r == 2);
    }
}